// Round 1
// baseline (7510.816 us; speedup 1.0000x reference)
//
#include <hip/hip_runtime.h>
#include <stdint.h>
#include <stddef.h>

#define T_   1024
#define BATCH 128
#define IN    512
#define HID  1024
#define OUTN  256

typedef unsigned short u16;
typedef __attribute__((ext_vector_type(8))) short short8;
typedef __attribute__((ext_vector_type(4))) float floatx4;

// Big scratch as device globals (d_ws size unknown). All fully rewritten every call.
__device__ u16 g_xbf[(size_t)BATCH * T_ * IN];        // x in bf16, [B*T][IN]
__device__ u16 g_kT[(size_t)HID * IN];                // kernel^T in bf16, [H][IN]
__device__ u16 g_xp[(size_t)BATCH * T_ * HID];        // x@kernel+bias, bf16, [B*T][H]
__device__ u16 g_h[2][(size_t)BATCH * HID];           // h ping-pong, bf16
__device__ unsigned long long g_ctr[8];               // per-group barrier counters

__device__ __forceinline__ u16 f2bf(float f) {
    uint32_t u = __builtin_bit_cast(uint32_t, f);
    u += 0x7fffu + ((u >> 16) & 1u);          // round-to-nearest-even
    return (u16)(u >> 16);
}
__device__ __forceinline__ float bf2f(u16 s) {
    uint32_t u = ((uint32_t)s) << 16;
    return __builtin_bit_cast(float, u);
}

__global__ void k_init() {
    if (threadIdx.x < 8) g_ctr[threadIdx.x] = 0ull;
}

// Convert x -> bf16 and kernel -> bf16 transposed (kT[n][k])
__global__ __launch_bounds__(256) void k_convert(const float* __restrict__ x,
                                                 const float* __restrict__ kern) {
    size_t i = (size_t)blockIdx.x * blockDim.x + threadIdx.x;
    size_t stride = (size_t)gridDim.x * blockDim.x;
    size_t n4 = (size_t)BATCH * T_ * IN / 4;
    for (size_t p = i; p < n4; p += stride) {
        float4 v = ((const float4*)x)[p];
        ushort4 o;
        o.x = f2bf(v.x); o.y = f2bf(v.y); o.z = f2bf(v.z); o.w = f2bf(v.w);
        ((ushort4*)g_xbf)[p] = o;
    }
    for (size_t p = i; p < (size_t)IN * HID; p += stride) {
        size_t k = p >> 10, n = p & 1023;        // read coalesced over n
        g_kT[n * IN + k] = f2bf(kern[p]);
    }
}

// xp = x @ kernel + bias   (M=131072, N=1024, K=512), bf16 MFMA, 128x128 tile
__global__ __launch_bounds__(256) void k_xp(const float* __restrict__ bias) {
    __shared__ u16 As[128][40];   // +8 pad: 2-way-only bank aliasing on b128 reads
    __shared__ u16 Bs[128][40];
    const int tid = threadIdx.x;
    const int bx = blockIdx.x & 7;       // n tile (8)
    const int by = blockIdx.x >> 3;      // m tile (1024)
    const int m0 = by * 128, n0 = bx * 128;
    const int lane = tid & 63, wave = tid >> 6;
    const int m_off = (wave & 1) * 64, n_off = (wave >> 1) * 64;
    const int sr = tid >> 1, skh = (tid & 1) * 16;

    floatx4 acc[4][4] = {};
    for (int k0 = 0; k0 < IN; k0 += 32) {
        const u16* ga = g_xbf + (size_t)(m0 + sr) * IN + k0 + skh;
        const u16* gb = g_kT  + (size_t)(n0 + sr) * IN + k0 + skh;
        int4 a0 = *(const int4*)ga, a1 = *(const int4*)(ga + 8);
        int4 b0 = *(const int4*)gb, b1 = *(const int4*)(gb + 8);
        __syncthreads();
        *(int4*)&As[sr][skh] = a0; *(int4*)&As[sr][skh + 8] = a1;
        *(int4*)&Bs[sr][skh] = b0; *(int4*)&Bs[sr][skh + 8] = b1;
        __syncthreads();
        short8 af[4], bf[4];
#pragma unroll
        for (int i = 0; i < 4; i++)
            af[i] = *(const short8*)&As[m_off + i * 16 + (lane & 15)][(lane >> 4) * 8];
#pragma unroll
        for (int j = 0; j < 4; j++)
            bf[j] = *(const short8*)&Bs[n_off + j * 16 + (lane & 15)][(lane >> 4) * 8];
#pragma unroll
        for (int i = 0; i < 4; i++)
#pragma unroll
            for (int j = 0; j < 4; j++)
                acc[i][j] = __builtin_amdgcn_mfma_f32_16x16x32_bf16(af[i], bf[j], acc[i][j], 0, 0, 0);
    }
    // epilogue: D layout col = lane&15, row = (lane>>4)*4 + reg  [m89-verified]
#pragma unroll
    for (int j = 0; j < 4; j++) {
        int n = n0 + n_off + j * 16 + (lane & 15);
        float bv = bias[n];
#pragma unroll
        for (int i = 0; i < 4; i++)
#pragma unroll
            for (int rr = 0; rr < 4; rr++) {
                int m = m0 + m_off + i * 16 + (lane >> 4) * 4 + rr;
                g_xp[(size_t)m * HID + n] = f2bf(acc[i][j][rr] + bv);
            }
    }
}

// Persistent scan: 128 WGs = 8 batch-groups (16 rows) x 16 j-tiles (64 cols).
// R^T tile resident in LDS; per-step group barrier via L3 atomics.
#define SCAN_LDS (64 * 1032 * 2 + 3 * 1024 * 4)
__global__ __launch_bounds__(256, 1) void k_scan(const float* __restrict__ R) {
    extern __shared__ char smem[];
    u16* Rs = (u16*)smem;                                   // [64][1032] (k-pad 8 -> 2-way banks)
    float* red = (float*)(smem + 64 * 1032 * 2);            // [3][1024] cross-wave reduce
    const int tid = threadIdx.x, lane = tid & 63, wave = tid >> 6;
    const int g = blockIdx.x, bt = g & 7, jt = g >> 3;      // same-bt WGs -> same XCD (heuristic)
    const int b0 = bt * 16, n0 = jt * 64;

    // Load R columns n0..n0+63 into LDS as Rs[n_local][k] (B-fragment friendly)
    {
        const int rrow = tid >> 4;           // 0..15
        const int c4 = (tid & 15) * 4;       // 0..60
        for (int k = rrow; k < HID; k += 16) {
            float4 v = *(const float4*)&R[(size_t)k * HID + n0 + c4];
            Rs[(size_t)(c4 + 0) * 1032 + k] = f2bf(v.x);
            Rs[(size_t)(c4 + 1) * 1032 + k] = f2bf(v.y);
            Rs[(size_t)(c4 + 2) * 1032 + k] = f2bf(v.z);
            Rs[(size_t)(c4 + 3) * 1032 + k] = f2bf(v.w);
        }
    }
    __syncthreads();

    for (int t = 0; t < T_; t++) {
        // xp prefetch (wave0 only; independent of barrier -> hides latency)
        float xpv[16];
        if (wave == 0) {
#pragma unroll
            for (int jr = 0; jr < 16; jr++) {
                int j = jr >> 2, rr = jr & 3;
                int m = (lane >> 4) * 4 + rr;
                int n = n0 + j * 16 + (lane & 15);
                xpv[jr] = bf2f(g_xp[((size_t)(b0 + m) * T_ + t) * HID + n]);
            }
        }
        floatx4 acc[4] = {};
        if (t > 0) {
            const u16* hb = g_h[t & 1];
            union { unsigned long long u[2]; short8 v; } afr[8];
            // K-split: wave w covers k in [w*256, w*256+256)
#pragma unroll
            for (int c = 0; c < 8; c++) {
                int k = wave * 256 + c * 32 + (lane >> 4) * 8;
                const unsigned long long* q =
                    (const unsigned long long*)(hb + (size_t)(b0 + (lane & 15)) * HID + k);
                afr[c].u[0] = __hip_atomic_load(q,     __ATOMIC_RELAXED, __HIP_MEMORY_SCOPE_AGENT);
                afr[c].u[1] = __hip_atomic_load(q + 1, __ATOMIC_RELAXED, __HIP_MEMORY_SCOPE_AGENT);
            }
#pragma unroll
            for (int c = 0; c < 8; c++) {
                int kl = wave * 256 + c * 32 + (lane >> 4) * 8;
#pragma unroll
                for (int j = 0; j < 4; j++) {
                    short8 bfr = *(const short8*)&Rs[(size_t)(j * 16 + (lane & 15)) * 1032 + kl];
                    acc[j] = __builtin_amdgcn_mfma_f32_16x16x32_bf16(afr[c].v, bfr, acc[j], 0, 0, 0);
                }
            }
        }
        if (wave > 0) {
#pragma unroll
            for (int j = 0; j < 4; j++)
#pragma unroll
                for (int rr = 0; rr < 4; rr++)
                    red[(wave - 1) * 1024 + (j * 4 + rr) * 64 + lane] = acc[j][rr];
        }
        __syncthreads();
        if (wave == 0) {
            u16* ho = g_h[(t + 1) & 1];
#pragma unroll
            for (int j = 0; j < 4; j++)
#pragma unroll
                for (int rr = 0; rr < 4; rr++) {
                    int idx = (j * 4 + rr) * 64 + lane;
                    float s = acc[j][rr] + red[idx] + red[1024 + idx] + red[2048 + idx] + xpv[j * 4 + rr];
                    float hv = tanhf(s);
                    int m = (lane >> 4) * 4 + rr;
                    int n = n0 + j * 16 + (lane & 15);
                    __hip_atomic_store(&ho[(size_t)(b0 + m) * HID + n], f2bf(hv),
                                       __ATOMIC_RELAXED, __HIP_MEMORY_SCOPE_AGENT);
                }
        }
        __syncthreads();   // drains wave0's stores (vmcnt) before arrival
        if (tid == 0) {
            __hip_atomic_fetch_add(&g_ctr[bt], 1ull, __ATOMIC_RELEASE, __HIP_MEMORY_SCOPE_AGENT);
            unsigned long long tgt = (unsigned long long)16 * (t + 1);
            long bail = 0;
            while (__hip_atomic_load(&g_ctr[bt], __ATOMIC_RELAXED, __HIP_MEMORY_SCOPE_AGENT) < tgt) {
                __builtin_amdgcn_s_sleep(1);
                if (++bail > (1L << 26)) break;   // deadlock fuse (never hit if co-resident)
            }
        }
        __syncthreads();
    }
}

// out = h_last @ fc_w + fc_b   (128 x 256)
__global__ __launch_bounds__(256) void k_final(const float* __restrict__ fcw,
                                               const float* __restrict__ fcb,
                                               float* __restrict__ out) {
    int b = blockIdx.x, o = threadIdx.x;
    const u16* h = g_h[0];   // h_1024 lives in buffer (1024 & 1) == 0
    float acc = fcb[o];
#pragma unroll 8
    for (int k = 0; k < HID; k++)
        acc += bf2f(h[(size_t)b * HID + k]) * fcw[(size_t)k * OUTN + o];
    out[(size_t)b * OUTN + o] = acc;
}

extern "C" void kernel_launch(void* const* d_in, const int* in_sizes, int n_in,
                              void* d_out, int out_size, void* d_ws, size_t ws_size,
                              hipStream_t stream) {
    const float* x    = (const float*)d_in[0];
    const float* kern = (const float*)d_in[1];
    const float* R    = (const float*)d_in[2];
    const float* bias = (const float*)d_in[3];
    const float* fcw  = (const float*)d_in[4];
    const float* fcb  = (const float*)d_in[5];
    float* out = (float*)d_out;

    k_init<<<1, 64, 0, stream>>>();
    k_convert<<<4096, 256, 0, stream>>>(x, kern);
    k_xp<<<8192, 256, 0, stream>>>(bias);
    (void)hipFuncSetAttribute((const void*)k_scan,
                              hipFuncAttributeMaxDynamicSharedMemorySize, SCAN_LDS);
    k_scan<<<128, 256, SCAN_LDS, stream>>>(R);
    k_final<<<128, 256, 0, stream>>>(fcw, fcb, out);
}